// Round 1
// baseline (2807.981 us; speedup 1.0000x reference)
//
#include <hip/hip_runtime.h>
#include <math.h>

#define BATCH 64
#define T 4096
#define ALPH 32
#define NS 128
#define NORM_EVERY 8

// ws float layout:
//   A_ws : [0, NS*NS)            row-stochastic A[k][s] (softmax over s)
//   Bm_ws: [NS*NS, NS*NS+ALPH*NS) emission Bm[a][s] (softmax over a per column s)
//   I_ws : next NS floats         initial distribution

__global__ void prep_kernel(const float* __restrict__ A_logits,
                            const float* __restrict__ B_logits,
                            const float* __restrict__ I_logits,
                            float* __restrict__ ws) {
    float* A_ws  = ws;
    float* Bm_ws = ws + NS * NS;
    float* I_ws  = ws + NS * NS + ALPH * NS;
    int blk = blockIdx.x;
    int tid = threadIdx.x;  // 128 threads

    if (blk == NS) {
        // Bm: column softmax over alphabet; thread = state s
        int s = tid;
        float m = -1e30f;
        for (int a = 0; a < ALPH; ++a) m = fmaxf(m, B_logits[a * NS + s]);
        float sum = 0.f;
        for (int a = 0; a < ALPH; ++a) sum += expf(B_logits[a * NS + s] - m);
        float inv = 1.0f / sum;
        for (int a = 0; a < ALPH; ++a)
            Bm_ws[a * NS + s] = expf(B_logits[a * NS + s] - m) * inv;
        return;
    }

    // blk < NS: row softmax of A row `blk`; blk == NS+1: softmax of I.
    const float* src = (blk < NS) ? (A_logits + blk * NS) : I_logits;
    float*       dst = (blk < NS) ? (A_ws + blk * NS) : I_ws;

    __shared__ float redm[2];
    __shared__ float reds[2];
    float x = src[tid];
    float m = x;
    #pragma unroll
    for (int off = 1; off < 64; off <<= 1) m = fmaxf(m, __shfl_xor(m, off));
    int wid = tid >> 6;
    if ((tid & 63) == 0) redm[wid] = m;
    __syncthreads();
    m = fmaxf(redm[0], redm[1]);
    float e = expf(x - m);
    float sg = e;
    #pragma unroll
    for (int off = 1; off < 64; off <<= 1) sg += __shfl_xor(sg, off);
    if ((tid & 63) == 0) reds[wid] = sg;
    __syncthreads();
    float total = reds[0] + reds[1];
    dst[tid] = e / total;
}

__global__ __launch_bounds__(256) void hmm_kernel(const float* __restrict__ onehot,
                                                  const float* __restrict__ ws,
                                                  float* __restrict__ out) {
    const float* A_ws  = ws;
    const float* Bm_ws = ws + NS * NS;
    const float* I_ws  = ws + NS * NS + ALPH * NS;

    const int b   = blockIdx.x;
    const int tid = threadIdx.x;
    const int s   = tid >> 1;   // state 0..127
    const int h   = tid & 1;    // k-half

    __shared__ float Bm_lds[ALPH * NS];
    __shared__ __align__(16) float alpha[2][NS];
    __shared__ unsigned char tok_lds[T];

    // stage Bm into LDS
    for (int i = tid; i < ALPH * NS; i += 256) Bm_lds[i] = Bm_ws[i];

    // extract tokens from the one-hot input (exact 1.0f entries)
    const float4* in4 = (const float4*)(onehot + (size_t)b * T * ALPH);
    for (int it = 0; it < T / 256; ++it) {
        int t = it * 256 + tid;
        const float4* p = in4 + (size_t)t * (ALPH / 4);
        int tk = 0;
        #pragma unroll
        for (int q = 0; q < 8; ++q) {
            float4 v = p[q];
            if (v.x > 0.5f) tk = 4 * q + 0;
            if (v.y > 0.5f) tk = 4 * q + 1;
            if (v.z > 0.5f) tk = 4 * q + 2;
            if (v.w > 0.5f) tk = 4 * q + 3;
        }
        tok_lds[t] = (unsigned char)tk;
    }

    // A column s, k-range [64h, 64h+64) into 64 VGPRs
    float4 Ar[16];
    #pragma unroll
    for (int j4 = 0; j4 < 16; ++j4) {
        int k = 64 * h + 4 * j4;
        Ar[j4].x = A_ws[(k + 0) * NS + s];
        Ar[j4].y = A_ws[(k + 1) * NS + s];
        Ar[j4].z = A_ws[(k + 2) * NS + s];
        Ar[j4].w = A_ws[(k + 3) * NS + s];
    }

    __syncthreads();

    // t = 0: alpha0 = I * E0 (unnormalized; first window absorbs the scale)
    if (tid < NS) {
        int tk0 = tok_lds[0];
        alpha[0][tid] = I_ws[tid] * Bm_lds[tk0 * NS + tid];
    }
    __syncthreads();

    float loglik = 0.0f;

    #pragma unroll 2
    for (int t = 1; t < T; ++t) {
        const float4* ap4 = (const float4*)&alpha[(t + 1) & 1][64 * h];
        float p = 0.0f;
        float asum = 0.0f;
        const bool do_norm = ((t & (NORM_EVERY - 1)) == 0);

        if (do_norm) {
            #pragma unroll
            for (int j4 = 0; j4 < 16; ++j4) {
                float4 av = ap4[j4];
                p = fmaf(av.x, Ar[j4].x, p);
                p = fmaf(av.y, Ar[j4].y, p);
                p = fmaf(av.z, Ar[j4].z, p);
                p = fmaf(av.w, Ar[j4].w, p);
                asum += av.x + av.y + av.z + av.w;
            }
        } else {
            #pragma unroll
            for (int j4 = 0; j4 < 16; ++j4) {
                float4 av = ap4[j4];
                p = fmaf(av.x, Ar[j4].x, p);
                p = fmaf(av.y, Ar[j4].y, p);
                p = fmaf(av.z, Ar[j4].z, p);
                p = fmaf(av.w, Ar[j4].w, p);
            }
        }

        float p2 = p + __shfl_xor(p, 1);          // full 128-dot for state s
        float e  = Bm_lds[(int)tok_lds[t] * NS + s];
        float v  = p2 * e;

        if (do_norm) {
            float tot = asum + __shfl_xor(asum, 1);  // sum of previous alpha (all 128)
            loglik += __logf(tot);
            v *= (1.0f / tot);
        }

        if (h == 0) alpha[t & 1][s] = v;
        __syncthreads();
    }

    // final window: loglik += log(sum(alpha_final))
    {
        const float4* ap4 = (const float4*)&alpha[(T - 1) & 1][64 * h];
        float asum = 0.0f;
        #pragma unroll
        for (int j4 = 0; j4 < 16; ++j4) {
            float4 av = ap4[j4];
            asum += av.x + av.y + av.z + av.w;
        }
        float tot = asum + __shfl_xor(asum, 1);
        loglik += __logf(tot);
        if (tid == 0) out[b] = loglik;
    }
}

extern "C" void kernel_launch(void* const* d_in, const int* in_sizes, int n_in,
                              void* d_out, int out_size, void* d_ws, size_t ws_size,
                              hipStream_t stream) {
    const float* onehot   = (const float*)d_in[0];
    const float* A_logits = (const float*)d_in[1];
    const float* B_logits = (const float*)d_in[2];
    const float* I_logits = (const float*)d_in[3];
    float* ws  = (float*)d_ws;
    float* out = (float*)d_out;

    prep_kernel<<<dim3(NS + 2), dim3(128), 0, stream>>>(A_logits, B_logits, I_logits, ws);
    hmm_kernel<<<dim3(BATCH), dim3(256), 0, stream>>>(onehot, ws, out);
}

// Round 2
// 397.368 us; speedup vs baseline: 7.0664x; 7.0664x over previous
//
#include <hip/hip_runtime.h>
#include <math.h>

#define BATCH 64
#define T 4096
#define ALPH 32
#define NS 128
#define NCHUNK 8
#define CHUNK_L (T / NCHUNK)   // 512
#define WARM 64                // warmup steps (multiple of 8)

// ws float layout:
//   A_ws : [0, NS*NS)                     row-stochastic A[k][s]
//   Bm_ws: [NS*NS, NS*NS+ALPH*NS)         emission Bm[a][s]
//   I_ws : next NS floats                 initial distribution
//   part : next BATCH*NCHUNK floats       per-chunk partial logliks
#define WS_A 0
#define WS_BM (NS * NS)
#define WS_I (NS * NS + ALPH * NS)
#define WS_PART (NS * NS + ALPH * NS + NS)

__global__ void prep_kernel(const float* __restrict__ A_logits,
                            const float* __restrict__ B_logits,
                            const float* __restrict__ I_logits,
                            float* __restrict__ ws) {
    float* A_ws  = ws + WS_A;
    float* Bm_ws = ws + WS_BM;
    float* I_ws  = ws + WS_I;
    int blk = blockIdx.x;
    int tid = threadIdx.x;  // 128 threads

    if (blk == NS) {
        // Bm: column softmax over alphabet; thread = state s
        int s = tid;
        float m = -1e30f;
        for (int a = 0; a < ALPH; ++a) m = fmaxf(m, B_logits[a * NS + s]);
        float sum = 0.f;
        for (int a = 0; a < ALPH; ++a) sum += expf(B_logits[a * NS + s] - m);
        float inv = 1.0f / sum;
        for (int a = 0; a < ALPH; ++a)
            Bm_ws[a * NS + s] = expf(B_logits[a * NS + s] - m) * inv;
        return;
    }

    const float* src = (blk < NS) ? (A_logits + blk * NS) : I_logits;
    float*       dst = (blk < NS) ? (A_ws + blk * NS) : I_ws;

    __shared__ float redm[2];
    __shared__ float reds[2];
    float x = src[tid];
    float m = x;
    #pragma unroll
    for (int off = 1; off < 64; off <<= 1) m = fmaxf(m, __shfl_xor(m, off));
    int wid = tid >> 6;
    if ((tid & 63) == 0) redm[wid] = m;
    __syncthreads();
    m = fmaxf(redm[0], redm[1]);
    float e = expf(x - m);
    float sg = e;
    #pragma unroll
    for (int off = 1; off < 64; off <<= 1) sg += __shfl_xor(sg, off);
    if ((tid & 63) == 0) reds[wid] = sg;
    __syncthreads();
    float total = reds[0] + reds[1];
    dst[tid] = e / total;
}

// One block per (batch, chunk). Chunk 0 starts exact (alpha0 = I*E0);
// chunks c>=1 start uniform at global index c*L-WARM and run WARM warmup
// steps whose scale factors are discarded (contraction makes the alpha
// direction exact to fp32 by the handoff point c*L-1).
__global__ __launch_bounds__(256) void hmm_kernel(const float* __restrict__ onehot,
                                                  const float* __restrict__ ws,
                                                  float* __restrict__ part) {
    const float* A_ws  = ws + WS_A;
    const float* Bm_ws = ws + WS_BM;
    const float* I_ws  = ws + WS_I;

    const int b   = blockIdx.x;
    const int c   = blockIdx.y;
    const int tid = threadIdx.x;
    const int s   = tid >> 1;   // state 0..127
    const int h   = tid & 1;    // k-half
    // second alpha half stored at dword offset 68 (not 64): the wave's two
    // broadcast addresses land in disjoint bank groups -> no conflicts.
    const int widx = (s < 64) ? s : (s + 4);

    __shared__ float Bm_lds[ALPH * NS];
    __shared__ __align__(16) float alpha[2][136];
    __shared__ unsigned char tok_lds[CHUNK_L + WARM];

    const int t0     = (c == 0) ? 0 : (c * CHUNK_L - WARM);
    const int ntok   = (c == 0) ? CHUNK_L : (CHUNK_L + WARM);
    const int nsteps = (c == 0) ? (CHUNK_L - 1) : (CHUNK_L + WARM - 1);
    const int resetj = (c == 0) ? -1 : WARM;

    // stage Bm into LDS
    for (int i = tid; i < ALPH * NS; i += 256) Bm_lds[i] = Bm_ws[i];

    // extract tokens for this chunk's range from the one-hot input
    const float4* in4 = (const float4*)(onehot + ((size_t)b * T + t0) * ALPH);
    for (int t = tid; t < ntok; t += 256) {
        const float4* p = in4 + (size_t)t * (ALPH / 4);
        int tk = 0;
        #pragma unroll
        for (int q = 0; q < 8; ++q) {
            float4 v = p[q];
            if (v.x > 0.5f) tk = 4 * q + 0;
            if (v.y > 0.5f) tk = 4 * q + 1;
            if (v.z > 0.5f) tk = 4 * q + 2;
            if (v.w > 0.5f) tk = 4 * q + 3;
        }
        tok_lds[t] = (unsigned char)tk;
    }

    // A column s, k-range [64h, 64h+64) into 64 VGPRs
    float4 Ar[16];
    #pragma unroll
    for (int j4 = 0; j4 < 16; ++j4) {
        int k = 64 * h + 4 * j4;
        Ar[j4].x = A_ws[(k + 0) * NS + s];
        Ar[j4].y = A_ws[(k + 1) * NS + s];
        Ar[j4].z = A_ws[(k + 2) * NS + s];
        Ar[j4].w = A_ws[(k + 3) * NS + s];
    }

    __syncthreads();

    // local alpha_0
    if (tid < NS) {
        float v;
        if (c == 0) {
            int tk0 = tok_lds[0];
            v = I_ws[tid] * Bm_lds[tk0 * NS + tid];
        } else {
            v = 1.0f;  // uniform start; scale discarded at reset
        }
        alpha[0][(tid < 64) ? tid : (tid + 4)] = v;
    }
    __syncthreads();

    float loglik = 0.0f;

    #pragma unroll 2
    for (int j = 1; j <= nsteps; ++j) {
        const float4* ap4 = (const float4*)(&alpha[(j + 1) & 1][68 * h]);
        const int tk = tok_lds[j];
        const float e = Bm_lds[tk * NS + s];
        const bool do_norm = ((j & 7) == 0);

        float4 av[16];
        #pragma unroll
        for (int i = 0; i < 16; ++i) av[i] = ap4[i];

        float p0 = 0.f, p1 = 0.f, p2 = 0.f, p3 = 0.f;
        #pragma unroll
        for (int i = 0; i < 16; i += 4) {
            p0 = fmaf(av[i + 0].x, Ar[i + 0].x, p0);
            p0 = fmaf(av[i + 0].y, Ar[i + 0].y, p0);
            p0 = fmaf(av[i + 0].z, Ar[i + 0].z, p0);
            p0 = fmaf(av[i + 0].w, Ar[i + 0].w, p0);
            p1 = fmaf(av[i + 1].x, Ar[i + 1].x, p1);
            p1 = fmaf(av[i + 1].y, Ar[i + 1].y, p1);
            p1 = fmaf(av[i + 1].z, Ar[i + 1].z, p1);
            p1 = fmaf(av[i + 1].w, Ar[i + 1].w, p1);
            p2 = fmaf(av[i + 2].x, Ar[i + 2].x, p2);
            p2 = fmaf(av[i + 2].y, Ar[i + 2].y, p2);
            p2 = fmaf(av[i + 2].z, Ar[i + 2].z, p2);
            p2 = fmaf(av[i + 2].w, Ar[i + 2].w, p2);
            p3 = fmaf(av[i + 3].x, Ar[i + 3].x, p3);
            p3 = fmaf(av[i + 3].y, Ar[i + 3].y, p3);
            p3 = fmaf(av[i + 3].z, Ar[i + 3].z, p3);
            p3 = fmaf(av[i + 3].w, Ar[i + 3].w, p3);
        }
        float p = (p0 + p1) + (p2 + p3);
        float v = (p + __shfl_xor(p, 1)) * e;  // full 128-dot * emission

        if (do_norm) {
            float a0 = 0.f, a1 = 0.f, a2 = 0.f, a3 = 0.f;
            #pragma unroll
            for (int i = 0; i < 16; i += 4) {
                a0 += av[i + 0].x + av[i + 0].y + av[i + 0].z + av[i + 0].w;
                a1 += av[i + 1].x + av[i + 1].y + av[i + 1].z + av[i + 1].w;
                a2 += av[i + 2].x + av[i + 2].y + av[i + 2].z + av[i + 2].w;
                a3 += av[i + 3].x + av[i + 3].y + av[i + 3].z + av[i + 3].w;
            }
            float asum = (a0 + a1) + (a2 + a3);
            float tot = asum + __shfl_xor(asum, 1);
            loglik += __logf(tot);
            v *= (1.0f / tot);
            if (j == resetj) loglik = 0.0f;  // discard warmup mass
        }

        if (h == 0) alpha[j & 1][widx] = v;
        __syncthreads();
    }

    // final flush: log(sum(alpha_last)) relative to last normalization
    {
        const float4* ap4 = (const float4*)(&alpha[nsteps & 1][68 * h]);
        float a0 = 0.f, a1 = 0.f;
        #pragma unroll
        for (int i = 0; i < 16; i += 2) {
            float4 v0 = ap4[i], v1 = ap4[i + 1];
            a0 += v0.x + v0.y + v0.z + v0.w;
            a1 += v1.x + v1.y + v1.z + v1.w;
        }
        float asum = a0 + a1;
        float tot = asum + __shfl_xor(asum, 1);
        loglik += __logf(tot);
        if (tid == 0) part[b * NCHUNK + c] = loglik;
    }
}

__global__ void reduce_kernel(const float* __restrict__ part, float* __restrict__ out) {
    int b = threadIdx.x;  // 64 threads
    float acc = 0.f;
    #pragma unroll
    for (int c = 0; c < NCHUNK; ++c) acc += part[b * NCHUNK + c];
    out[b] = acc;
}

extern "C" void kernel_launch(void* const* d_in, const int* in_sizes, int n_in,
                              void* d_out, int out_size, void* d_ws, size_t ws_size,
                              hipStream_t stream) {
    const float* onehot   = (const float*)d_in[0];
    const float* A_logits = (const float*)d_in[1];
    const float* B_logits = (const float*)d_in[2];
    const float* I_logits = (const float*)d_in[3];
    float* ws  = (float*)d_ws;
    float* out = (float*)d_out;

    prep_kernel<<<dim3(NS + 2), dim3(128), 0, stream>>>(A_logits, B_logits, I_logits, ws);
    hmm_kernel<<<dim3(BATCH, NCHUNK), dim3(256), 0, stream>>>(onehot, ws, ws + WS_PART);
    reduce_kernel<<<dim3(1), dim3(BATCH), 0, stream>>>(ws + WS_PART, out);
}

// Round 4
// 130.196 us; speedup vs baseline: 21.5674x; 3.0521x over previous
//
#include <hip/hip_runtime.h>
#include <math.h>

#define BATCH 64
#define T 4096
#define ALPH 32
#define NS 128
#define MB 16              // batches per block (MFMA M)
#define NGRP (BATCH / MB)  // 4
#define NCHUNK 64
#define CL (T / NCHUNK)    // 64
#define WARM 32            // multiple of 8

typedef __bf16 bf16x8 __attribute__((ext_vector_type(8)));
typedef short  short8 __attribute__((ext_vector_type(8)));
typedef float  f32x4  __attribute__((ext_vector_type(4)));

// ws layout (float offsets unless noted):
//   A_bf : ushort[NS*NS]      at float-offset 0      (8192 floats)
//   Bm   : float[ALPH*NS]     at 8192
//   I    : float[NS]          at 12288
//   part : float[BATCH*NCHUNK] at 12416
//   tok  : uchar[BATCH*T]     at 16512
#define WS_ABF 0
#define WS_BM 8192
#define WS_I 12288
#define WS_PART 12416
#define WS_TOK_F 16512

static __device__ inline short f2s(float f) {
    __bf16 b = (__bf16)f;
    return __builtin_bit_cast(short, b);
}

__global__ void prep_kernel(const float* __restrict__ A_logits,
                            const float* __restrict__ B_logits,
                            const float* __restrict__ I_logits,
                            float* __restrict__ ws) {
    unsigned short* A_bf = (unsigned short*)(ws + WS_ABF);
    float* Bm_ws = ws + WS_BM;
    float* I_ws  = ws + WS_I;
    int blk = blockIdx.x;
    int tid = threadIdx.x;  // 128 threads

    if (blk == NS) {
        // Bm: column softmax over alphabet; thread = state s
        int s = tid;
        float m = -1e30f;
        for (int a = 0; a < ALPH; ++a) m = fmaxf(m, B_logits[a * NS + s]);
        float sum = 0.f;
        for (int a = 0; a < ALPH; ++a) sum += expf(B_logits[a * NS + s] - m);
        float inv = 1.0f / sum;
        for (int a = 0; a < ALPH; ++a)
            Bm_ws[a * NS + s] = expf(B_logits[a * NS + s] - m) * inv;
        return;
    }

    const float* src = (blk < NS) ? (A_logits + blk * NS) : I_logits;

    __shared__ float redm[2];
    __shared__ float reds[2];
    float x = src[tid];
    float m = x;
    #pragma unroll
    for (int off = 1; off < 64; off <<= 1) m = fmaxf(m, __shfl_xor(m, off));
    int wid = tid >> 6;
    if ((tid & 63) == 0) redm[wid] = m;
    __syncthreads();
    m = fmaxf(redm[0], redm[1]);
    float e = expf(x - m);
    float sg = e;
    #pragma unroll
    for (int off = 1; off < 64; off <<= 1) sg += __shfl_xor(sg, off);
    if ((tid & 63) == 0) reds[wid] = sg;
    __syncthreads();
    float total = reds[0] + reds[1];
    float v = e / total;
    if (blk < NS) A_bf[blk * NS + tid] = (unsigned short)f2s(v);
    else          I_ws[tid] = v;
}

// Extract token ids from the one-hot input. Grid (BATCH, T/256) x 256.
__global__ void tok_kernel(const float* __restrict__ onehot,
                           unsigned char* __restrict__ tok) {
    int b = blockIdx.x;
    int t = blockIdx.y * 256 + threadIdx.x;
    const float4* p = (const float4*)(onehot + ((size_t)b * T + t) * ALPH);
    int tk = 0;
    #pragma unroll
    for (int q = 0; q < 8; ++q) {
        float4 v = p[q];
        if (v.x > 0.5f) tk = 4 * q + 0;
        if (v.y > 0.5f) tk = 4 * q + 1;
        if (v.z > 0.5f) tk = 4 * q + 2;
        if (v.w > 0.5f) tk = 4 * q + 3;
    }
    tok[(size_t)b * T + t] = (unsigned char)tk;
}

// One block per (batch-group g, chunk c). 16 chains advance together via
// MFMA: new_alpha[16x128] = (alpha[16x128] . A[128x128]) * E_t, bf16 in LDS.
// Normalization windows capture the NEW v's sum (scale through step j), so
// chunk c owns global steps t = c*CL+1 .. (c+1)*CL; the warmup ledger is
// DISCARDED at j=WARM (t=c*CL, owned by chunk c-1). Chunk 0 owns t=0..CL.
__global__ __launch_bounds__(256) void hmm_kernel(const float* __restrict__ ws,
                                                  const unsigned char* __restrict__ tok_g,
                                                  float* __restrict__ part) {
    const unsigned short* A_bf = (const unsigned short*)(ws + WS_ABF);
    const float* Bm_g = ws + WS_BM;
    const float* I_ws = ws + WS_I;

    const int g = blockIdx.x;   // batch group
    const int c = blockIdx.y;   // chunk
    const int tid  = threadIdx.x;
    const int w    = tid >> 6;       // wave 0..3 -> states [32w, 32w+32)
    const int lane = tid & 63;
    const int quad = lane >> 4;
    const int col  = lane & 15;
    const int nbase = w * 32;

    __shared__ float Bm_lds[ALPH * 129];                       // stride 129: no quad conflicts
    __shared__ __align__(16) short alpha_lds[2][MB * 136];     // bf16, row stride 136 shorts
    __shared__ unsigned char tok_lds[(CL + WARM + 1) * MB];    // [t][m]
    __shared__ __align__(16) float s_part[64];
    __shared__ float llsum[MB];

    const int t0     = (c == 0) ? 0 : (c * CL - WARM);
    const int nsteps = (c == 0) ? CL
                     : ((c == NCHUNK - 1) ? (CL + WARM - 1) : (CL + WARM));
    const int ntok   = nsteps + 1;
    const int resetj = (c == 0) ? -1 : WARM;

    // stage Bm (padded stride) and tokens [t][m]
    for (int i = tid; i < ALPH * NS; i += 256)
        Bm_lds[(i >> 7) * 129 + (i & 127)] = Bm_g[i];
    for (int i = tid; i < ntok * MB; i += 256) {
        int m = i & (MB - 1);
        int t = i >> 4;
        tok_lds[i] = tok_g[(size_t)(g * MB + m) * T + t0 + t];
    }
    if (tid < MB) llsum[tid] = 0.f;

    // B-operand fragments of the transition matrix: b[kc][nt] holds
    // A[k = kc*32 + quad*8 + j][n = nbase + nt*16 + col], j = 0..7
    bf16x8 bfr[4][2];
    #pragma unroll
    for (int kc = 0; kc < 4; ++kc) {
        #pragma unroll
        for (int nt = 0; nt < 2; ++nt) {
            short8 bs;
            #pragma unroll
            for (int j = 0; j < 8; ++j)
                bs[j] = (short)A_bf[(kc * 32 + quad * 8 + j) * NS + nbase + nt * 16 + col];
            bfr[kc][nt] = __builtin_bit_cast(bf16x8, bs);
        }
    }

    __syncthreads();

    // initial alpha (bf16): chunk 0 exact (I * E_0), others uniform
    {
        int m = tid >> 4;
        int seg = tid & 15;
        int tk0 = tok_lds[m];
        #pragma unroll
        for (int kk = 0; kk < 8; ++kk) {
            int k = seg * 8 + kk;
            float val = (c == 0) ? (I_ws[k] * Bm_lds[tk0 * 129 + k]) : 1.0f;
            alpha_lds[0][m * 136 + k] = f2s(val);
        }
    }
    __syncthreads();

    for (int j = 1; j <= nsteps; ++j) {
        const int rb = (j + 1) & 1;
        const int wb = j & 1;
        const bool do_norm = ((j & 7) == 0);

        // A-operand fragments: lane holds alpha[m=col][k = kc*32 + quad*8 + jj]
        const short* ap = &alpha_lds[rb][col * 136 + quad * 8];
        bf16x8 afr[4];
        #pragma unroll
        for (int kc = 0; kc < 4; ++kc)
            afr[kc] = *(const bf16x8*)(ap + kc * 32);

        f32x4 acc0 = {0.f, 0.f, 0.f, 0.f};
        f32x4 acc1 = {0.f, 0.f, 0.f, 0.f};
        #pragma unroll
        for (int kc = 0; kc < 4; ++kc) {
            acc0 = __builtin_amdgcn_mfma_f32_16x16x32_bf16(afr[kc], bfr[kc][0], acc0, 0, 0, 0);
            acc1 = __builtin_amdgcn_mfma_f32_16x16x32_bf16(afr[kc], bfr[kc][1], acc1, 0, 0, 0);
        }

        // emission multiply; lane's rows m = quad*4 + r, cols nbase+nt*16+col
        unsigned tokp = *(const unsigned*)&tok_lds[j * MB + quad * 4];
        float v0[4], v1[4];
        #pragma unroll
        for (int r = 0; r < 4; ++r) {
            int tk = (tokp >> (8 * r)) & 255;
            v0[r] = acc0[r] * Bm_lds[tk * 129 + nbase + col];
            v1[r] = acc1[r] * Bm_lds[tk * 129 + nbase + 16 + col];
        }

        if (do_norm) {
            float pr[4];
            #pragma unroll
            for (int r = 0; r < 4; ++r) pr[r] = v0[r] + v1[r];
            #pragma unroll
            for (int off = 1; off < 16; off <<= 1) {
                #pragma unroll
                for (int r = 0; r < 4; ++r) pr[r] += __shfl_xor(pr[r], off);
            }
            if (col == 0) {
                float4* dst = (float4*)&s_part[w * 16 + quad * 4];
                *dst = make_float4(pr[0], pr[1], pr[2], pr[3]);
            }
            __syncthreads();
            float sm[4];
            #pragma unroll
            for (int r = 0; r < 4; ++r) {
                float acc = 0.f;
                #pragma unroll
                for (int w2 = 0; w2 < 4; ++w2) acc += s_part[w2 * 16 + quad * 4 + r];
                sm[r] = acc;
            }
            if (w == 0 && col == 0) {
                #pragma unroll
                for (int r = 0; r < 4; ++r) {
                    float lg = __logf(sm[r]);
                    // discard the ledger at the warmup handoff: the window
                    // ending at j=WARM covers t <= c*CL, owned by chunk c-1
                    llsum[quad * 4 + r] = (j == resetj) ? 0.0f : (llsum[quad * 4 + r] + lg);
                }
            }
            #pragma unroll
            for (int r = 0; r < 4; ++r) {
                float inv = __builtin_amdgcn_rcpf(sm[r]);
                v0[r] *= inv;
                v1[r] *= inv;
            }
        }

        // write new alpha (bf16)
        #pragma unroll
        for (int r = 0; r < 4; ++r) {
            int row = (quad * 4 + r) * 136;
            alpha_lds[wb][row + nbase + col]      = f2s(v0[r]);
            alpha_lds[wb][row + nbase + 16 + col] = f2s(v1[r]);
        }
        __syncthreads();
    }

    // final flush: loglik[m] = llsum[m] + log(sum_k alpha_final[m][k])
    {
        const int rb = nsteps & 1;
        const short* ap = &alpha_lds[rb][col * 136 + quad * 8];
        float tot = 0.f;
        #pragma unroll
        for (int kc = 0; kc < 4; ++kc) {
            bf16x8 av = *(const bf16x8*)(ap + kc * 32);
            #pragma unroll
            for (int jj = 0; jj < 8; ++jj) tot += (float)av[jj];
        }
        tot += __shfl_xor(tot, 16);
        tot += __shfl_xor(tot, 32);
        if (tid < MB) part[(size_t)(g * MB + tid) * NCHUNK + c] = llsum[tid] + __logf(tot);
    }
}

__global__ void reduce_kernel(const float* __restrict__ part, float* __restrict__ out) {
    int b = threadIdx.x;  // 64 threads
    float acc = 0.f;
    #pragma unroll
    for (int c = 0; c < NCHUNK; ++c) acc += part[b * NCHUNK + c];
    out[b] = acc;
}

extern "C" void kernel_launch(void* const* d_in, const int* in_sizes, int n_in,
                              void* d_out, int out_size, void* d_ws, size_t ws_size,
                              hipStream_t stream) {
    const float* onehot   = (const float*)d_in[0];
    const float* A_logits = (const float*)d_in[1];
    const float* B_logits = (const float*)d_in[2];
    const float* I_logits = (const float*)d_in[3];
    float* ws  = (float*)d_ws;
    float* out = (float*)d_out;
    unsigned char* tok = (unsigned char*)(ws + WS_TOK_F);

    prep_kernel<<<dim3(NS + 2), dim3(128), 0, stream>>>(A_logits, B_logits, I_logits, ws);
    tok_kernel<<<dim3(BATCH, T / 256), dim3(256), 0, stream>>>(onehot, tok);
    hmm_kernel<<<dim3(NGRP, NCHUNK), dim3(256), 0, stream>>>(ws, tok, ws + WS_PART);
    reduce_kernel<<<dim3(1), dim3(BATCH), 0, stream>>>(ws + WS_PART, out);
}

// Round 5
// 111.572 us; speedup vs baseline: 25.1674x; 1.1669x over previous
//
#include <hip/hip_runtime.h>
#include <math.h>

#define BATCH 64
#define T 4096
#define ALPH 32
#define NS 128
#define MB 16              // batches per block (MFMA M)
#define NGRP (BATCH / MB)  // 4
#define NCHUNK 256
#define CL (T / NCHUNK)    // 16
#define WARM 16            // multiple of 8

typedef __bf16 bf16x8 __attribute__((ext_vector_type(8)));
typedef short  short8 __attribute__((ext_vector_type(8)));
typedef float  f32x4  __attribute__((ext_vector_type(4)));

// ws layout (float offsets):
//   A_bf : ushort[NS*NS]   at 0
//   Bm   : float[ALPH*NS]  at 8192
//   I    : float[NS]       at 12288
//   tok  : uchar[BATCH*T]  at 12416
#define WS_ABF 0
#define WS_BM 8192
#define WS_I 12288
#define WS_TOK_F 12416

static __device__ inline short f2s(float f) {
    __bf16 b = (__bf16)f;
    return __builtin_bit_cast(short, b);
}

// Fused setup: blocks [0,1024) extract tokens; blocks [1024,1153) do the
// A-row / I softmaxes; block 1153 does the Bm column softmax + zeroes out.
__global__ __launch_bounds__(256) void setup_kernel(const float* __restrict__ onehot,
                                                    const float* __restrict__ A_logits,
                                                    const float* __restrict__ B_logits,
                                                    const float* __restrict__ I_logits,
                                                    float* __restrict__ ws,
                                                    float* __restrict__ out,
                                                    unsigned char* __restrict__ tok) {
    unsigned short* A_bf = (unsigned short*)(ws + WS_ABF);
    float* Bm_ws = ws + WS_BM;
    float* I_ws  = ws + WS_I;
    const int blk = blockIdx.x;
    const int tid = threadIdx.x;

    if (blk < 1024) {
        // token extraction: 16 tiles of 256 per batch
        int b = blk >> 4;
        int t = (blk & 15) * 256 + tid;
        const float4* p = (const float4*)(onehot + ((size_t)b * T + t) * ALPH);
        int tk = 0;
        #pragma unroll
        for (int q = 0; q < 8; ++q) {
            float4 v = p[q];
            if (v.x > 0.5f) tk = 4 * q + 0;
            if (v.y > 0.5f) tk = 4 * q + 1;
            if (v.z > 0.5f) tk = 4 * q + 2;
            if (v.w > 0.5f) tk = 4 * q + 3;
        }
        tok[(size_t)b * T + t] = (unsigned char)tk;
        return;
    }

    if (blk == 1024 + NS + 1) {
        // Bm: column softmax over alphabet (thread = state), plus zero out[]
        if (tid < NS) {
            int s = tid;
            float m = -1e30f;
            for (int a = 0; a < ALPH; ++a) m = fmaxf(m, B_logits[a * NS + s]);
            float sum = 0.f;
            for (int a = 0; a < ALPH; ++a) sum += expf(B_logits[a * NS + s] - m);
            float inv = 1.0f / sum;
            for (int a = 0; a < ALPH; ++a)
                Bm_ws[a * NS + s] = expf(B_logits[a * NS + s] - m) * inv;
        } else if (tid < NS + BATCH) {
            out[tid - NS] = 0.0f;
        }
        return;
    }

    // A-row (row<NS) or I (row==NS) softmax over 128 elems, 256 threads
    int row = blk - 1024;
    const float* src = (row < NS) ? (A_logits + row * NS) : I_logits;
    __shared__ float redm[4];
    __shared__ float reds[4];
    float x = (tid < NS) ? src[tid] : -1e30f;
    float m = x;
    #pragma unroll
    for (int off = 1; off < 64; off <<= 1) m = fmaxf(m, __shfl_xor(m, off));
    int wid = tid >> 6;
    if ((tid & 63) == 0) redm[wid] = m;
    __syncthreads();
    m = fmaxf(fmaxf(redm[0], redm[1]), fmaxf(redm[2], redm[3]));
    float e = (tid < NS) ? expf(x - m) : 0.0f;
    float sg = e;
    #pragma unroll
    for (int off = 1; off < 64; off <<= 1) sg += __shfl_xor(sg, off);
    if ((tid & 63) == 0) reds[wid] = sg;
    __syncthreads();
    float total = (reds[0] + reds[1]) + (reds[2] + reds[3]);
    float v = e / total;
    if (tid < NS) {
        if (row < NS) A_bf[row * NS + tid] = (unsigned short)f2s(v);
        else          I_ws[tid] = v;
    }
}

// One block per (batch-group g, chunk c). 16 chains advance together via
// MFMA. Read-side normalization: on norm steps the OLD alpha's 128-sum is
// computed per-lane from the A-fragments (identical across waves) with two
// shuffles — no cross-wave reduction, one barrier per step. Old-sum ledger:
// chunk c owns global steps t = c*CL .. c*CL+CL-1; warmup mass discarded at
// j=WARM. Chunk 0 starts exact from I*E_0.
__global__ __launch_bounds__(256) void hmm_kernel(const float* __restrict__ ws,
                                                  const unsigned char* __restrict__ tok_g,
                                                  float* __restrict__ out) {
    const unsigned short* A_bf = (const unsigned short*)(ws + WS_ABF);
    const float* Bm_g = ws + WS_BM;
    const float* I_ws = ws + WS_I;

    const int g = blockIdx.x;   // batch group
    const int c = blockIdx.y;   // chunk
    const int tid  = threadIdx.x;
    const int w    = tid >> 6;       // wave 0..3 -> states [32w, 32w+32)
    const int lane = tid & 63;
    const int quad = lane >> 4;
    const int col  = lane & 15;
    const int nbase = w * 32;

    __shared__ float Bm_lds[ALPH * 129];                      // stride 129
    __shared__ __align__(16) short alpha_lds[2][MB * 136];    // bf16, row stride 136 shorts
    __shared__ unsigned char tok_lds[(CL + WARM + 1) * MB];   // [t][m]

    const int t0     = (c == 0) ? 0 : (c * CL - WARM);
    const int nsteps = (c == 0) ? (CL - 1) : (CL + WARM - 1);
    const int ntok   = nsteps + 1;
    const int resetj = (c == 0) ? -1 : WARM;

    // stage Bm (padded stride) and tokens [t][m]
    for (int i = tid; i < ALPH * NS; i += 256)
        Bm_lds[(i >> 7) * 129 + (i & 127)] = Bm_g[i];
    for (int i = tid; i < ntok * MB; i += 256) {
        int m = i & (MB - 1);
        int t = i >> 4;
        tok_lds[i] = tok_g[(size_t)(g * MB + m) * T + t0 + t];
    }

    // B-operand fragments: bfr[kc][nt] holds A[k=kc*32+quad*8+j][nbase+nt*16+col]
    bf16x8 bfr[4][2];
    #pragma unroll
    for (int kc = 0; kc < 4; ++kc) {
        #pragma unroll
        for (int nt = 0; nt < 2; ++nt) {
            short8 bs;
            #pragma unroll
            for (int j = 0; j < 8; ++j)
                bs[j] = (short)A_bf[(kc * 32 + quad * 8 + j) * NS + nbase + nt * 16 + col];
            bfr[kc][nt] = __builtin_bit_cast(bf16x8, bs);
        }
    }

    __syncthreads();

    // initial alpha (bf16): chunk 0 exact (I * E_0), others uniform
    {
        int m = tid >> 4;
        int seg = tid & 15;
        int tk0 = tok_lds[m];
        #pragma unroll
        for (int kk = 0; kk < 8; ++kk) {
            int k = seg * 8 + kk;
            float val = (c == 0) ? (I_ws[k] * Bm_lds[tk0 * 129 + k]) : 1.0f;
            alpha_lds[0][m * 136 + k] = f2s(val);
        }
    }
    __syncthreads();

    float loglik = 0.0f;  // per-lane ledger for batch row m = col (redundant across quads/waves)

    for (int j = 1; j <= nsteps; ++j) {
        const int rb = (j + 1) & 1;
        const int wb = j & 1;
        const bool do_norm = ((j & 7) == 0);

        // emission values first (independent of alpha -> hides LDS latency)
        unsigned tokp = *(const unsigned*)&tok_lds[j * MB + quad * 4];
        float e0[4], e1[4];
        #pragma unroll
        for (int r = 0; r < 4; ++r) {
            int tk = (tokp >> (8 * r)) & 255;
            e0[r] = Bm_lds[tk * 129 + nbase + col];
            e1[r] = Bm_lds[tk * 129 + nbase + 16 + col];
        }

        // A-operand fragments: lane holds alpha[m=col][k = kc*32 + quad*8 + jj]
        const short* ap = &alpha_lds[rb][col * 136 + quad * 8];
        bf16x8 afr[4];
        #pragma unroll
        for (int kc = 0; kc < 4; ++kc)
            afr[kc] = *(const bf16x8*)(ap + kc * 32);

        f32x4 acc0 = {0.f, 0.f, 0.f, 0.f};
        f32x4 acc1 = {0.f, 0.f, 0.f, 0.f};
        #pragma unroll
        for (int kc = 0; kc < 4; ++kc) {
            acc0 = __builtin_amdgcn_mfma_f32_16x16x32_bf16(afr[kc], bfr[kc][0], acc0, 0, 0, 0);
            acc1 = __builtin_amdgcn_mfma_f32_16x16x32_bf16(afr[kc], bfr[kc][1], acc1, 0, 0, 0);
        }

        float v0[4], v1[4];
        #pragma unroll
        for (int r = 0; r < 4; ++r) {
            v0[r] = acc0[r] * e0[r];
            v1[r] = acc1[r] * e1[r];
        }

        if (do_norm) {
            // old-alpha 128-sum for row m=col, from this lane's own fragments
            float asum = 0.f;
            #pragma unroll
            for (int kc = 0; kc < 4; ++kc) {
                #pragma unroll
                for (int jj = 0; jj < 8; ++jj) asum += (float)afr[kc][jj];
            }
            asum += __shfl_xor(asum, 16);
            asum += __shfl_xor(asum, 32);
            float lg = __logf(asum);
            loglik = (j == resetj) ? 0.0f : (loglik + lg);
            float inv = __builtin_amdgcn_rcpf(asum);
            #pragma unroll
            for (int r = 0; r < 4; ++r) { v0[r] *= inv; v1[r] *= inv; }
        }

        // write new alpha (bf16)
        #pragma unroll
        for (int r = 0; r < 4; ++r) {
            int row = (quad * 4 + r) * 136;
            alpha_lds[wb][row + nbase + col]      = f2s(v0[r]);
            alpha_lds[wb][row + nbase + 16 + col] = f2s(v1[r]);
        }
        __syncthreads();
    }

    // final flush: loglik[m] += log(sum_k alpha_final[m][k]); one atomic per m
    {
        const short* ap = &alpha_lds[nsteps & 1][col * 136 + quad * 8];
        float tot = 0.f;
        #pragma unroll
        for (int kc = 0; kc < 4; ++kc) {
            bf16x8 av = *(const bf16x8*)(ap + kc * 32);
            #pragma unroll
            for (int jj = 0; jj < 8; ++jj) tot += (float)av[jj];
        }
        tot += __shfl_xor(tot, 16);
        tot += __shfl_xor(tot, 32);
        if (w == 0 && quad == 0)
            atomicAdd(out + g * MB + col, loglik + __logf(tot));
    }
}

extern "C" void kernel_launch(void* const* d_in, const int* in_sizes, int n_in,
                              void* d_out, int out_size, void* d_ws, size_t ws_size,
                              hipStream_t stream) {
    const float* onehot   = (const float*)d_in[0];
    const float* A_logits = (const float*)d_in[1];
    const float* B_logits = (const float*)d_in[2];
    const float* I_logits = (const float*)d_in[3];
    float* ws  = (float*)d_ws;
    float* out = (float*)d_out;
    unsigned char* tok = (unsigned char*)(ws + WS_TOK_F);

    setup_kernel<<<dim3(1024 + NS + 2), dim3(256), 0, stream>>>(
        onehot, A_logits, B_logits, I_logits, ws, out, tok);
    hmm_kernel<<<dim3(NGRP, NCHUNK), dim3(256), 0, stream>>>(ws, tok, out);
}